// Round 1
// baseline (1199.251 us; speedup 1.0000x reference)
//
#include <hip/hip_runtime.h>
#include <hip/hip_bf16.h>

// bf16 helpers ---------------------------------------------------------------
typedef short short8 __attribute__((ext_vector_type(8)));
typedef float f32x4 __attribute__((ext_vector_type(4)));

__device__ __forceinline__ unsigned short f2bf(float f) {
    __hip_bfloat16 h = __float2bfloat16(f);
    return __builtin_bit_cast(unsigned short, h);
}
__device__ __forceinline__ float bflo(unsigned int u) {
    return __builtin_bit_cast(float, u << 16);
}
__device__ __forceinline__ float bfhi(unsigned int u) {
    return __builtin_bit_cast(float, u & 0xffff0000u);
}

// fp32 -> bf16 elementwise (vectorized float4 in, ushort4 out) ---------------
__global__ __launch_bounds__(256) void conv_f32_to_bf16(
    const float* __restrict__ in, unsigned short* __restrict__ out, int n4) {
    int i = blockIdx.x * 256 + threadIdx.x;
    if (i >= n4) return;
    float4 v = ((const float4*)in)[i];
    ushort4 o;
    o.x = f2bf(v.x); o.y = f2bf(v.y); o.z = f2bf(v.z); o.w = f2bf(v.w);
    ((ushort4*)out)[i] = o;
}

// W[K][N] fp32 -> WT[N][K] bf16, LDS-tiled transpose (both sides coalesced) --
__global__ __launch_bounds__(256) void transpose_f32_to_bf16(
    const float* __restrict__ W, unsigned short* __restrict__ WT, int K, int N) {
    __shared__ float tile[32][33];
    int tx = threadIdx.x, ty = threadIdx.y;
    int n0 = blockIdx.x * 32, k0 = blockIdx.y * 32;
#pragma unroll
    for (int j = 0; j < 4; ++j)
        tile[ty + j * 8][tx] = W[(size_t)(k0 + ty + j * 8) * N + n0 + tx];
    __syncthreads();
#pragma unroll
    for (int j = 0; j < 4; ++j)
        WT[(size_t)(n0 + ty + j * 8) * K + k0 + tx] = f2bf(tile[tx][ty + j * 8]);
}

// C[M,N] (bf16 or f32) = A[M,K]bf16 @ Bt[N,K]bf16^T + bias[N]
// 128x128 tile, BK=32, 256 threads = 4 waves (2x2), each wave 64x64 (4x4 frags)
template <bool OUT_BF16>
__global__ __launch_bounds__(256, 2) void gemm_bt(
    const unsigned short* __restrict__ A,
    const unsigned short* __restrict__ Bt,
    const float* __restrict__ bias,
    void* __restrict__ Cout,
    int M, int N, int K) {
    __shared__ unsigned short sA[128][32];
    __shared__ unsigned short sB[128][32];
    const int tid = threadIdx.x;
    const int lane = tid & 63;
    const int w = tid >> 6;
    const int wr = (w >> 1) * 64;  // wave row offset in tile
    const int wc = (w & 1) * 64;   // wave col offset in tile
    const size_t arow0 = (size_t)blockIdx.x * 128;
    const size_t brow0 = (size_t)blockIdx.y * 128;
    const int rowS = tid >> 1;            // staging row 0..127
    const int scol = (tid & 1) << 4;      // staging col (ushort units): 0 or 16

    f32x4 acc[4][4] = {};

    const unsigned short* pA = A + (arow0 + rowS) * (size_t)K + scol;
    const unsigned short* pB = Bt + (brow0 + rowS) * (size_t)K + scol;

    for (int k0 = 0; k0 < K; k0 += 32) {
        __syncthreads();  // previous iter's fragment reads done
        uint4 a0 = *(const uint4*)(pA + k0);
        uint4 a1 = *(const uint4*)(pA + k0 + 8);
        uint4 b0 = *(const uint4*)(pB + k0);
        uint4 b1 = *(const uint4*)(pB + k0 + 8);
        *(uint4*)&sA[rowS][scol] = a0;
        *(uint4*)&sA[rowS][scol + 8] = a1;
        *(uint4*)&sB[rowS][scol] = b0;
        *(uint4*)&sB[rowS][scol + 8] = b1;
        __syncthreads();

        const int fr = lane & 15;
        const int fk = (lane >> 4) << 3;  // 0,8,16,24
        short8 af[4], bfr[4];
#pragma unroll
        for (int i = 0; i < 4; ++i) af[i] = *(const short8*)&sA[wr + i * 16 + fr][fk];
#pragma unroll
        for (int i = 0; i < 4; ++i) bfr[i] = *(const short8*)&sB[wc + i * 16 + fr][fk];
#pragma unroll
        for (int mi = 0; mi < 4; ++mi) {
#pragma unroll
            for (int ni = 0; ni < 4; ++ni) {
                acc[mi][ni] = __builtin_amdgcn_mfma_f32_16x16x32_bf16(
                    af[mi], bfr[ni], acc[mi][ni], 0, 0, 0);
            }
        }
    }

    // epilogue: C/D layout col=lane&15, row=(lane>>4)*4+j  [measured m89]
    const int fr = lane & 15;
    const int fq = (lane >> 4) << 2;
#pragma unroll
    for (int mi = 0; mi < 4; ++mi) {
#pragma unroll
        for (int ni = 0; ni < 4; ++ni) {
            size_t r = arow0 + wr + mi * 16 + fq;
            size_t c = brow0 + wc + ni * 16 + fr;
            float bv = bias[c];
#pragma unroll
            for (int j = 0; j < 4; ++j) {
                float v = acc[mi][ni][j] + bv;
                if constexpr (OUT_BF16)
                    ((unsigned short*)Cout)[(r + j) * (size_t)N + c] = f2bf(v);
                else
                    ((float*)Cout)[(r + j) * (size_t)N + c] = v;
            }
        }
    }
}

// fp32 flash attention: 1 block = (b,h,64 q rows); 4 waves split the s-range;
// lane owns one q row (Q,O in regs); per-wave K/V chunk staged bf16->f32 LDS;
// final cross-wave online-softmax combine through LDS.
__global__ __launch_bounds__(256, 2) void attn_flash(
    const unsigned short* __restrict__ qkv,  // [B*T, 3072] bf16 (q|k|v)
    unsigned short* __restrict__ y,          // [B*T, 1024] bf16
    int BH) {
    constexpr int T = 2048;
    constexpr int H = 16;
    constexpr float SCALE = 0.125f;  // 1/sqrt(64)

    __shared__ float smem[4 * 64 * 64 + 512];  // 64KB combine region + m/l
    float* sM = smem + 16384;
    float* sL = smem + 16640;

    const int tid = threadIdx.x;
    const int lane = tid & 63;
    const int w = tid >> 6;
    const int blk = blockIdx.x;
    const int bh = blk % BH;
    const int qt = 31 - blk / BH;  // heavy q-tiles dispatched first
    const int b = bh / H, h = bh % H;
    const int r_base = qt * 64;
    const int r_row = r_base + lane;

    float* myK = smem + w * 2048;  // [16][64] f32, per-wave private
    float* myV = myK + 1024;

    // load this lane's Q row, pre-scaled
    float Q[64];
    {
        const unsigned short* qp = qkv + (size_t)(b * T + r_row) * 3072 + h * 64;
#pragma unroll
        for (int i = 0; i < 16; ++i) {
            uint2 qv = *(const uint2*)(qp + i * 4);
            Q[i * 4 + 0] = bflo(qv.x) * SCALE;
            Q[i * 4 + 1] = bfhi(qv.x) * SCALE;
            Q[i * 4 + 2] = bflo(qv.y) * SCALE;
            Q[i * 4 + 3] = bfhi(qv.y) * SCALE;
        }
    }

    float O[64] = {};
    float m = -1e30f, l = 0.f;

    const unsigned short* kvbase = qkv + (size_t)b * T * 3072 + 1024 + h * 64;
    const int nch4 = qt + 1;  // 16-wide s-chunks per wave (equal across waves)
    for (int ci = w * nch4; ci < (w + 1) * nch4; ++ci) {
        const int sb = ci * 16;
        __syncthreads();  // everyone done reading previous chunk
        // stage K/V rows sb..sb+15 (bf16 -> f32)
#pragma unroll
        for (int j = 0; j < 4; ++j) {
            int u = lane + j * 64;
            int sr = u >> 4;
            int c4 = (u & 15) << 2;
            const unsigned short* kp = kvbase + (size_t)(sb + sr) * 3072 + c4;
            uint2 kv = *(const uint2*)kp;
            uint2 vv = *(const uint2*)(kp + 1024);
            float4 kf = make_float4(bflo(kv.x), bfhi(kv.x), bflo(kv.y), bfhi(kv.y));
            float4 vf = make_float4(bflo(vv.x), bfhi(vv.x), bflo(vv.y), bfhi(vv.y));
            *(float4*)&myK[sr * 64 + c4] = kf;
            *(float4*)&myV[sr * 64 + c4] = vf;
        }
        __syncthreads();

        // scores for 16 s-positions (K reads are wave-uniform -> LDS broadcast)
        float sc[16];
#pragma unroll
        for (int s = 0; s < 16; ++s) {
            float a0 = 0, a1 = 0, a2 = 0, a3 = 0;
#pragma unroll
            for (int d4 = 0; d4 < 16; ++d4) {
                float4 kf = *(const float4*)&myK[s * 64 + d4 * 4];
                a0 = fmaf(Q[d4 * 4 + 0], kf.x, a0);
                a1 = fmaf(Q[d4 * 4 + 1], kf.y, a1);
                a2 = fmaf(Q[d4 * 4 + 2], kf.z, a2);
                a3 = fmaf(Q[d4 * 4 + 3], kf.w, a3);
            }
            sc[s] = (a0 + a1) + (a2 + a3);
        }
        // causal mask + chunk max
        float mx = -1e30f;
#pragma unroll
        for (int s = 0; s < 16; ++s) {
            float t = (sb + s <= r_row) ? sc[s] : -1e30f;
            sc[s] = t;
            mx = fmaxf(mx, t);
        }
        float mn = fmaxf(m, mx);
        float fs = __expf(m - mn);  // ==1 when nothing valid yet (m==mn)
        float psum = 0.f;
#pragma unroll
        for (int s = 0; s < 16; ++s) {
            float p = (sc[s] > -1e29f) ? __expf(sc[s] - mn) : 0.f;  // masked -> 0
            sc[s] = p;
            psum += p;
        }
        l = l * fs + psum;
#pragma unroll
        for (int d = 0; d < 64; ++d) O[d] *= fs;
#pragma unroll
        for (int s = 0; s < 16; ++s) {
            float p = sc[s];
#pragma unroll
            for (int d4 = 0; d4 < 16; ++d4) {
                float4 vf = *(const float4*)&myV[s * 64 + d4 * 4];
                O[d4 * 4 + 0] = fmaf(p, vf.x, O[d4 * 4 + 0]);
                O[d4 * 4 + 1] = fmaf(p, vf.y, O[d4 * 4 + 1]);
                O[d4 * 4 + 2] = fmaf(p, vf.z, O[d4 * 4 + 2]);
                O[d4 * 4 + 3] = fmaf(p, vf.w, O[d4 * 4 + 3]);
            }
        }
        m = mn;
    }

    __syncthreads();  // all waves done with flash (K/V regions now dead)
    // write partials: O transposed sOT[w][d][r] so stores are conflict-free
    sM[w * 64 + lane] = m;
    sL[w * 64 + lane] = l;
#pragma unroll
    for (int d = 0; d < 64; ++d) smem[w * 4096 + d * 64 + lane] = O[d];
    __syncthreads();

    // combine 4 wave-partials per row; thread t -> (row=t>>2, d0=(t&3)*16)
    {
        const int r = tid >> 2;
        const int d0 = (tid & 3) << 4;
        float m0 = sM[r], m1 = sM[64 + r], m2 = sM[128 + r], m3 = sM[192 + r];
        float M2 = fmaxf(fmaxf(m0, m1), fmaxf(m2, m3));
        float f0 = __expf(m0 - M2), f1 = __expf(m1 - M2);
        float f2 = __expf(m2 - M2), f3 = __expf(m3 - M2);
        float L = f0 * sL[r] + f1 * sL[64 + r] + f2 * sL[128 + r] + f3 * sL[192 + r];
        float inv = 1.0f / L;
        unsigned int pw[8];
#pragma unroll
        for (int i2 = 0; i2 < 8; ++i2) {
            int da = d0 + i2 * 2, db = da + 1;
            float oa = f0 * smem[da * 64 + r] + f1 * smem[4096 + da * 64 + r] +
                       f2 * smem[8192 + da * 64 + r] + f3 * smem[12288 + da * 64 + r];
            float ob = f0 * smem[db * 64 + r] + f1 * smem[4096 + db * 64 + r] +
                       f2 * smem[8192 + db * 64 + r] + f3 * smem[12288 + db * 64 + r];
            pw[i2] = (unsigned int)f2bf(oa * inv) | ((unsigned int)f2bf(ob * inv) << 16);
        }
        size_t yi = (size_t)(b * T + r_base + r) * 1024 + h * 64 + d0;
        uint4 q0; q0.x = pw[0]; q0.y = pw[1]; q0.z = pw[2]; q0.w = pw[3];
        uint4 q1; q1.x = pw[4]; q1.y = pw[5]; q1.z = pw[6]; q1.w = pw[7];
        *(uint4*)&y[yi] = q0;
        *(uint4*)&y[yi + 8] = q1;
    }
}

extern "C" void kernel_launch(void* const* d_in, const int* in_sizes, int n_in,
                              void* d_out, int out_size, void* d_ws, size_t ws_size,
                              hipStream_t stream) {
    const float* x      = (const float*)d_in[0];
    const float* w_attn = (const float*)d_in[1];
    const float* b_attn = (const float*)d_in[2];
    const float* w_proj = (const float*)d_in[3];
    const float* b_proj = (const float*)d_in[4];

    const int C = 1024, T = 2048, H = 16;
    const int B = in_sizes[0] / (T * C);
    const int M = B * T;

    // workspace layout (ushorts): xb | wTa | wTp | qkv ; y reuses xb
    unsigned short* xb  = (unsigned short*)d_ws;          // M*C
    unsigned short* wTa = xb + (size_t)M * C;             // 3C x C
    unsigned short* wTp = wTa + (size_t)3 * C * C;        // C x C
    unsigned short* qkv = wTp + (size_t)C * C;            // M x 3C
    unsigned short* y   = xb;                              // reuse (xb dead after GEMM1)

    // 1) x -> bf16
    int n4 = (M * C) / 4;
    conv_f32_to_bf16<<<(n4 + 255) / 256, 256, 0, stream>>>(x, xb, n4);
    // 2) transpose weights to [N][K] bf16
    transpose_f32_to_bf16<<<dim3(3 * C / 32, C / 32), dim3(32, 8), 0, stream>>>(
        w_attn, wTa, C, 3 * C);
    transpose_f32_to_bf16<<<dim3(C / 32, C / 32), dim3(32, 8), 0, stream>>>(
        w_proj, wTp, C, C);
    // 3) qkv = x @ w_attn + b_attn (bf16 out)
    gemm_bt<true><<<dim3(M / 128, (3 * C) / 128), 256, 0, stream>>>(
        xb, wTa, b_attn, (void*)qkv, M, 3 * C, C);
    // 4) flash attention -> y bf16
    attn_flash<<<dim3(B * H * (T / 64)), 256, 0, stream>>>(qkv, y, B * H);
    // 5) out = y @ w_proj + b_proj (fp32 out)
    gemm_bt<false><<<dim3(M / 128, C / 128), 256, 0, stream>>>(
        y, wTp, b_proj, d_out, M, C, C);
}

// Round 2
// 266.410 us; speedup vs baseline: 4.5015x; 4.5015x over previous
//
#include <hip/hip_runtime.h>
#include <hip/hip_bf16.h>

typedef short short8 __attribute__((ext_vector_type(8)));
typedef float f32x4 __attribute__((ext_vector_type(4)));

__device__ __forceinline__ unsigned short f2bf(float f) {
    __hip_bfloat16 h = __float2bfloat16(f);
    return __builtin_bit_cast(unsigned short, h);
}

// ---- fp32 -> bf16 elementwise ----------------------------------------------
__global__ __launch_bounds__(256) void conv_f32_to_bf16(
    const float* __restrict__ in, unsigned short* __restrict__ out, int n4) {
    int i = blockIdx.x * 256 + threadIdx.x;
    if (i >= n4) return;
    float4 v = ((const float4*)in)[i];
    ushort4 o;
    o.x = f2bf(v.x); o.y = f2bf(v.y); o.z = f2bf(v.z); o.w = f2bf(v.w);
    ((ushort4*)out)[i] = o;
}

// ---- W[K][N] fp32 -> WT[N][K] bf16 -----------------------------------------
__global__ __launch_bounds__(256) void transpose_f32_to_bf16(
    const float* __restrict__ W, unsigned short* __restrict__ WT, int K, int N) {
    __shared__ float tile[32][33];
    int tx = threadIdx.x, ty = threadIdx.y;
    int n0 = blockIdx.x * 32, k0 = blockIdx.y * 32;
#pragma unroll
    for (int j = 0; j < 4; ++j)
        tile[ty + j * 8][tx] = W[(size_t)(k0 + ty + j * 8) * N + n0 + tx];
    __syncthreads();
#pragma unroll
    for (int j = 0; j < 4; ++j)
        WT[(size_t)(n0 + ty + j * 8) * K + k0 + tx] = f2bf(tile[tx][ty + j * 8]);
}

// ---- GEMM: C[M,N] = A[M,K]bf16 @ Bt[N,K]^T + bias --------------------------
// MODE 0: fp32 out, stride N.
// MODE 2: qkv split: cols<2048 -> bf16 qk[r][c] (stride 2048);
//         cols>=2048 -> bf16 vt[(b*1024 + c-2048)][t] (transposed V).
template <int MODE>
__global__ __launch_bounds__(256, 2) void gemm_bt(
    const unsigned short* __restrict__ A,
    const unsigned short* __restrict__ Bt,
    const float* __restrict__ bias,
    void* __restrict__ out0,
    unsigned short* __restrict__ out1,
    int M, int N, int K) {
    __shared__ unsigned short sA[128][32];
    __shared__ unsigned short sB[128][32];
    const int tid = threadIdx.x;
    const int lane = tid & 63;
    const int w = tid >> 6;
    const int wr = (w >> 1) * 64;
    const int wc = (w & 1) * 64;
    const size_t arow0 = (size_t)blockIdx.x * 128;
    const size_t brow0 = (size_t)blockIdx.y * 128;
    const int rowS = tid >> 1;
    const int scol = (tid & 1) << 4;

    f32x4 acc[4][4] = {};

    const unsigned short* pA = A + (arow0 + rowS) * (size_t)K + scol;
    const unsigned short* pB = Bt + (brow0 + rowS) * (size_t)K + scol;

    for (int k0 = 0; k0 < K; k0 += 32) {
        __syncthreads();
        uint4 a0 = *(const uint4*)(pA + k0);
        uint4 a1 = *(const uint4*)(pA + k0 + 8);
        uint4 b0 = *(const uint4*)(pB + k0);
        uint4 b1 = *(const uint4*)(pB + k0 + 8);
        *(uint4*)&sA[rowS][scol] = a0;
        *(uint4*)&sA[rowS][scol + 8] = a1;
        *(uint4*)&sB[rowS][scol] = b0;
        *(uint4*)&sB[rowS][scol + 8] = b1;
        __syncthreads();

        const int fr = lane & 15;
        const int fk = (lane >> 4) << 3;
        short8 af[4], bfr[4];
#pragma unroll
        for (int i = 0; i < 4; ++i) af[i] = *(const short8*)&sA[wr + i * 16 + fr][fk];
#pragma unroll
        for (int i = 0; i < 4; ++i) bfr[i] = *(const short8*)&sB[wc + i * 16 + fr][fk];
#pragma unroll
        for (int mi = 0; mi < 4; ++mi)
#pragma unroll
            for (int ni = 0; ni < 4; ++ni)
                acc[mi][ni] = __builtin_amdgcn_mfma_f32_16x16x32_bf16(
                    af[mi], bfr[ni], acc[mi][ni], 0, 0, 0);
    }

    const int fr = lane & 15;
    const int fq = (lane >> 4) << 2;
    if constexpr (MODE == 0) {
#pragma unroll
        for (int mi = 0; mi < 4; ++mi)
#pragma unroll
            for (int ni = 0; ni < 4; ++ni) {
                size_t r = arow0 + wr + mi * 16 + fq;
                size_t c = brow0 + wc + ni * 16 + fr;
                float bv = bias[c];
#pragma unroll
                for (int j = 0; j < 4; ++j)
                    ((float*)out0)[(r + j) * (size_t)N + c] = acc[mi][ni][j] + bv;
            }
    } else {
        const bool isv = (int)(brow0 + wc) >= 2048;
        if (isv) {
#pragma unroll
            for (int mi = 0; mi < 4; ++mi)
#pragma unroll
                for (int ni = 0; ni < 4; ++ni) {
                    int c = (int)brow0 + wc + ni * 16 + fr;
                    float bv = bias[c];
                    int cv = c - 2048;
                    int r0 = (int)arow0 + wr + mi * 16 + fq;
                    int bb = r0 >> 11, t0 = r0 & 2047;
                    unsigned int lo = (unsigned int)f2bf(acc[mi][ni][0] + bv) |
                                      ((unsigned int)f2bf(acc[mi][ni][1] + bv) << 16);
                    unsigned int hi = (unsigned int)f2bf(acc[mi][ni][2] + bv) |
                                      ((unsigned int)f2bf(acc[mi][ni][3] + bv) << 16);
                    *(uint2*)&out1[(((size_t)(bb * 1024 + cv)) << 11) + t0] =
                        make_uint2(lo, hi);
                }
        } else {
#pragma unroll
            for (int mi = 0; mi < 4; ++mi)
#pragma unroll
                for (int ni = 0; ni < 4; ++ni) {
                    size_t r = arow0 + wr + mi * 16 + fq;
                    size_t c = brow0 + wc + ni * 16 + fr;
                    float bv = bias[c];
#pragma unroll
                    for (int j = 0; j < 4; ++j)
                        ((unsigned short*)out0)[(r + j) * 2048 + c] =
                            f2bf(acc[mi][ni][j] + bv);
                }
        }
    }
}

// ---- MFMA flash attention ---------------------------------------------------
// Block: 128 q-rows (4 waves x 32), s-tiles of 64. K and V^T staged in LDS
// with XOR-16B swizzle; P re-fragmented via per-wave swizzled LDS buffer.
__global__ __launch_bounds__(256, 2) void attn_mfma(
    const unsigned short* __restrict__ qk,  // [B*T][2048] bf16 (q|k)
    const unsigned short* __restrict__ vt,  // [(b*1024+h*64+d)][T] bf16
    unsigned short* __restrict__ y,         // [B*T][1024] bf16
    int BH) {
    constexpr int T = 2048;
    constexpr float SCALE = 0.125f;  // 1/sqrt(64)

    __shared__ __align__(16) unsigned short sK[64 * 64];
    __shared__ __align__(16) unsigned short sV[64 * 64];  // V^T tile [d][s]
    __shared__ __align__(16) unsigned short sP[4][32 * 64];

    const int tid = threadIdx.x;
    const int lane = tid & 63;
    const int w = tid >> 6;
    const int l15 = lane & 15;
    const int g = lane >> 4;

    const int bh = blockIdx.x % BH;
    const int qt = 15 - blockIdx.x / BH;  // heavy q-tiles first
    const int b = bh >> 4;
    const int h = bh & 15;
    const int q0 = qt * 128;
    const int qw0 = q0 + w * 32;

    // Q fragments (A-frag: row=lane&15, k=(lane>>4)*8 within K=32 chunk)
    short8 aq[2][2];
    {
        const unsigned short* qbase = qk + ((size_t)(b * T + qw0)) * 2048 + h * 64;
#pragma unroll
        for (int mi = 0; mi < 2; ++mi)
#pragma unroll
            for (int kc = 0; kc < 2; ++kc)
                aq[mi][kc] = *(const short8*)(qbase + (size_t)(mi * 16 + l15) * 2048 +
                                              g * 8 + kc * 32);
    }

    f32x4 O[2][4] = {};
    float m_st[2][4], l_st[2][4];
#pragma unroll
    for (int mi = 0; mi < 2; ++mi)
#pragma unroll
        for (int r = 0; r < 4; ++r) { m_st[mi][r] = -1e30f; l_st[mi][r] = 0.f; }

    const unsigned short* kbase = qk + ((size_t)(b * T)) * 2048 + 1024 + h * 64;
    const unsigned short* vbase = vt + ((size_t)(b * 1024 + h * 64)) * 2048;
    unsigned short* sPw = sP[w];

    const int srow = tid >> 3;   // staging row 0..31 (+32)
    const int c16 = tid & 7;     // 16B column within 128B row

    const int nt = (q0 + 128) >> 6;
    for (int it = 0; it < nt; ++it) {
        const int s0 = it << 6;
        __syncthreads();
#pragma unroll
        for (int rep = 0; rep < 2; ++rep) {
            const int r = srow + rep * 32;
            uint4 kd = *(const uint4*)(kbase + (size_t)(s0 + r) * 2048 + c16 * 8);
            uint4 vd = *(const uint4*)(vbase + (size_t)r * 2048 + s0 + c16 * 8);
            *(uint4*)&sK[r * 64 + ((c16 ^ (r & 7)) << 3)] = kd;
            *(uint4*)&sV[r * 64 + ((c16 ^ (r & 7)) << 3)] = vd;
        }
        __syncthreads();
        if (s0 > qw0 + 31) continue;  // fully masked for this wave

        // ---- S = Q @ K^T ----
        f32x4 sacc[2][4] = {};
        {
            short8 bk[4][2];
#pragma unroll
            for (int ni = 0; ni < 4; ++ni) {
                const int row = ni * 16 + l15;
#pragma unroll
                for (int kc = 0; kc < 2; ++kc)
                    bk[ni][kc] = *(const short8*)&sK[row * 64 +
                                                     (((g + kc * 4) ^ (row & 7)) << 3)];
            }
#pragma unroll
            for (int kc = 0; kc < 2; ++kc)
#pragma unroll
                for (int mi = 0; mi < 2; ++mi)
#pragma unroll
                    for (int ni = 0; ni < 4; ++ni)
                        sacc[mi][ni] = __builtin_amdgcn_mfma_f32_16x16x32_bf16(
                            aq[mi][kc], bk[ni][kc], sacc[mi][ni], 0, 0, 0);
        }

        // ---- online softmax (wave-parallel, 16-lane xor reduce) ----
        float f_sc[2][4];
#pragma unroll
        for (int mi = 0; mi < 2; ++mi) {
#pragma unroll
            for (int reg = 0; reg < 4; ++reg) {
                const int q_loc = mi * 16 + g * 4 + reg;
                const int qg = q0 + w * 32 + q_loc;
                float mx = -INFINITY;
#pragma unroll
                for (int ni = 0; ni < 4; ++ni) {
                    float v = sacc[mi][ni][reg] * SCALE;
                    v = (s0 + ni * 16 + l15 <= qg) ? v : -INFINITY;
                    sacc[mi][ni][reg] = v;
                    mx = fmaxf(mx, v);
                }
                mx = fmaxf(mx, __shfl_xor(mx, 1));
                mx = fmaxf(mx, __shfl_xor(mx, 2));
                mx = fmaxf(mx, __shfl_xor(mx, 4));
                mx = fmaxf(mx, __shfl_xor(mx, 8));
                const float mn = fmaxf(m_st[mi][reg], mx);
                const float f = __expf(m_st[mi][reg] - mn);
                m_st[mi][reg] = mn;
                f_sc[mi][reg] = f;
                float rs = 0.f;
#pragma unroll
                for (int ni = 0; ni < 4; ++ni) {
                    float p = __expf(sacc[mi][ni][reg] - mn);
                    rs += p;
                    const int s = ni * 16 + l15;
                    sPw[q_loc * 64 + ((((s >> 3) ^ (q_loc & 7)) << 3) | (s & 7))] = f2bf(p);
                }
                rs += __shfl_xor(rs, 1);
                rs += __shfl_xor(rs, 2);
                rs += __shfl_xor(rs, 4);
                rs += __shfl_xor(rs, 8);
                l_st[mi][reg] = l_st[mi][reg] * f + rs;
            }
        }

        // ---- rescale O ----
#pragma unroll
        for (int mi = 0; mi < 2; ++mi)
#pragma unroll
            for (int di = 0; di < 4; ++di)
#pragma unroll
                for (int reg = 0; reg < 4; ++reg)
                    O[mi][di][reg] *= f_sc[mi][reg];

        // ---- O += P @ V ----
        short8 aP[2][2], bv[4][2];
#pragma unroll
        for (int mi = 0; mi < 2; ++mi) {
            const int row = mi * 16 + l15;
#pragma unroll
            for (int kc = 0; kc < 2; ++kc)
                aP[mi][kc] = *(const short8*)&sPw[row * 64 +
                                                  (((g + kc * 4) ^ (row & 7)) << 3)];
        }
#pragma unroll
        for (int di = 0; di < 4; ++di) {
            const int row = di * 16 + l15;
#pragma unroll
            for (int kc = 0; kc < 2; ++kc)
                bv[di][kc] = *(const short8*)&sV[row * 64 +
                                                 (((g + kc * 4) ^ (row & 7)) << 3)];
        }
#pragma unroll
        for (int kc = 0; kc < 2; ++kc)
#pragma unroll
            for (int mi = 0; mi < 2; ++mi)
#pragma unroll
                for (int di = 0; di < 4; ++di)
                    O[mi][di] = __builtin_amdgcn_mfma_f32_16x16x32_bf16(
                        aP[mi][kc], bv[di][kc], O[mi][di], 0, 0, 0);
    }

    // ---- normalize + write ----
#pragma unroll
    for (int mi = 0; mi < 2; ++mi) {
#pragma unroll
        for (int reg = 0; reg < 4; ++reg) {
            const float inv = 1.0f / l_st[mi][reg];
            const int q = q0 + w * 32 + mi * 16 + g * 4 + reg;
            const size_t base = (size_t)(b * T + q) * 1024 + h * 64 + l15;
#pragma unroll
            for (int di = 0; di < 4; ++di)
                y[base + di * 16] = f2bf(O[mi][di][reg] * inv);
        }
    }
}

extern "C" void kernel_launch(void* const* d_in, const int* in_sizes, int n_in,
                              void* d_out, int out_size, void* d_ws, size_t ws_size,
                              hipStream_t stream) {
    const float* x      = (const float*)d_in[0];
    const float* w_attn = (const float*)d_in[1];
    const float* b_attn = (const float*)d_in[2];
    const float* w_proj = (const float*)d_in[3];
    const float* b_proj = (const float*)d_in[4];

    const int C = 1024, T = 2048, H = 16;
    const int B = in_sizes[0] / (T * C);
    const int M = B * T;

    // workspace (ushorts): xb | wTa | wTp | qk | vt   (75.5 MB total)
    unsigned short* xb  = (unsigned short*)d_ws;          // M*C
    unsigned short* wTa = xb + (size_t)M * C;             // 3C x C
    unsigned short* wTp = wTa + (size_t)3 * C * C;        // C x C
    unsigned short* qkb = wTp + (size_t)C * C;            // M x 2C
    unsigned short* vtb = qkb + (size_t)M * 2 * C;        // B*1024 x T
    unsigned short* y   = xb;                             // reuse after GEMM1

    int n4 = (M * C) / 4;
    conv_f32_to_bf16<<<(n4 + 255) / 256, 256, 0, stream>>>(x, xb, n4);
    transpose_f32_to_bf16<<<dim3(3 * C / 32, C / 32), dim3(32, 8), 0, stream>>>(
        w_attn, wTa, C, 3 * C);
    transpose_f32_to_bf16<<<dim3(C / 32, C / 32), dim3(32, 8), 0, stream>>>(
        w_proj, wTp, C, C);
    gemm_bt<2><<<dim3(M / 128, (3 * C) / 128), 256, 0, stream>>>(
        xb, wTa, b_attn, (void*)qkb, vtb, M, 3 * C, C);
    attn_mfma<<<dim3(B * H * (T / 128)), 256, 0, stream>>>(qkb, vtb, y, B * H);
    gemm_bt<0><<<dim3(M / 128, C / 128), 256, 0, stream>>>(
        y, wTp, b_proj, d_out, nullptr, M, C, C);
}

// Round 3
// 224.346 us; speedup vs baseline: 5.3455x; 1.1875x over previous
//
#include <hip/hip_runtime.h>
#include <hip/hip_bf16.h>

typedef short short8 __attribute__((ext_vector_type(8)));
typedef float f32x4 __attribute__((ext_vector_type(4)));

typedef __attribute__((address_space(1))) void as1_void;
typedef __attribute__((address_space(3))) void as3_void;

__device__ __forceinline__ unsigned short f2bf(float f) {
    __hip_bfloat16 h = __float2bfloat16(f);
    return __builtin_bit_cast(unsigned short, h);
}

// async global->LDS, 16B per lane; lds dest = wave-uniform base + lane*16
__device__ __forceinline__ void gload16(const unsigned short* g, unsigned short* l) {
    __builtin_amdgcn_global_load_lds((as1_void*)g, (as3_void*)l, 16, 0, 0);
}

// ---- fp32 -> bf16 elementwise ----------------------------------------------
__global__ __launch_bounds__(256) void conv_f32_to_bf16(
    const float* __restrict__ in, unsigned short* __restrict__ out, int n4) {
    int i = blockIdx.x * 256 + threadIdx.x;
    if (i >= n4) return;
    float4 v = ((const float4*)in)[i];
    ushort4 o;
    o.x = f2bf(v.x); o.y = f2bf(v.y); o.z = f2bf(v.z); o.w = f2bf(v.w);
    ((ushort4*)out)[i] = o;
}

// ---- W[K][N] fp32 -> WT[N][K] bf16 -----------------------------------------
__global__ __launch_bounds__(256) void transpose_f32_to_bf16(
    const float* __restrict__ W, unsigned short* __restrict__ WT, int K, int N) {
    __shared__ float tile[32][33];
    int tx = threadIdx.x, ty = threadIdx.y;
    int n0 = blockIdx.x * 32, k0 = blockIdx.y * 32;
#pragma unroll
    for (int j = 0; j < 4; ++j)
        tile[ty + j * 8][tx] = W[(size_t)(k0 + ty + j * 8) * N + n0 + tx];
    __syncthreads();
#pragma unroll
    for (int j = 0; j < 4; ++j)
        WT[(size_t)(n0 + ty + j * 8) * K + k0 + tx] = f2bf(tile[tx][ty + j * 8]);
}

// ---- GEMM: C[M,N] = A[M,K]bf16 @ Bt[N,K]^T + bias --------------------------
// global_load_lds staging (m97 structure). MODE 0: fp32 out, stride N.
// MODE 2: qkv split: cols<1024 -> bf16 q*0.125; 1024..2047 -> bf16 k;
//         cols>=2048 -> bf16 vt[(b*1024 + c-2048)][t] (transposed V).
template <int MODE>
__global__ __launch_bounds__(256, 2) void gemm_bt(
    const unsigned short* __restrict__ A,
    const unsigned short* __restrict__ Bt,
    const float* __restrict__ bias,
    void* __restrict__ out0,
    unsigned short* __restrict__ out1,
    int M, int N, int K) {
    __shared__ unsigned short sA[128 * 32];
    __shared__ unsigned short sB[128 * 32];
    const int tid = threadIdx.x;
    const int lane = tid & 63;
    const int w = tid >> 6;
    const int wr = (w >> 1) * 64;
    const int wc = (w & 1) * 64;
    const size_t arow0 = (size_t)blockIdx.x * 128;
    const size_t brow0 = (size_t)blockIdx.y * 128;

    // staging: wave w owns rows [w*32, w*32+32); lane l -> row w*32+(l>>2),
    // 16B chunk (l&3). Two issues per operand (16 rows each), LDS linear.
    const int grow = (w << 5) + (lane >> 2);
    const int gcol = (lane & 3) << 3;
    const unsigned short* pA0 = A + (arow0 + grow) * (size_t)K + gcol;
    const unsigned short* pB0 = Bt + (brow0 + grow) * (size_t)K + gcol;
    unsigned short* lA = sA + (w << 10);
    unsigned short* lB = sB + (w << 10);

    f32x4 acc[4][4] = {};
    const int fr = lane & 15;
    const int fk = (lane >> 4) << 3;

    for (int k0 = 0; k0 < K; k0 += 32) {
        __syncthreads();  // previous iter's fragment reads done
        gload16(pA0 + k0, lA);
        gload16(pA0 + 16 * (size_t)K + k0, lA + 512);
        gload16(pB0 + k0, lB);
        gload16(pB0 + 16 * (size_t)K + k0, lB + 512);
        __syncthreads();  // vmcnt(0) drain before barrier makes LDS visible

        short8 af[4], bfr[4];
#pragma unroll
        for (int i = 0; i < 4; ++i)
            af[i] = *(const short8*)&sA[(wr + i * 16 + fr) * 32 + fk];
#pragma unroll
        for (int i = 0; i < 4; ++i)
            bfr[i] = *(const short8*)&sB[(wc + i * 16 + fr) * 32 + fk];
#pragma unroll
        for (int mi = 0; mi < 4; ++mi)
#pragma unroll
            for (int ni = 0; ni < 4; ++ni)
                acc[mi][ni] = __builtin_amdgcn_mfma_f32_16x16x32_bf16(
                    af[mi], bfr[ni], acc[mi][ni], 0, 0, 0);
    }

    const int fq = (lane >> 4) << 2;
    if constexpr (MODE == 0) {
#pragma unroll
        for (int mi = 0; mi < 4; ++mi)
#pragma unroll
            for (int ni = 0; ni < 4; ++ni) {
                size_t r = arow0 + wr + mi * 16 + fq;
                size_t c = brow0 + wc + ni * 16 + fr;
                float bv = bias[c];
#pragma unroll
                for (int j = 0; j < 4; ++j)
                    ((float*)out0)[(r + j) * (size_t)N + c] = acc[mi][ni][j] + bv;
            }
    } else {
        const bool isv = (int)(brow0 + wc) >= 2048;
        if (isv) {
#pragma unroll
            for (int mi = 0; mi < 4; ++mi)
#pragma unroll
                for (int ni = 0; ni < 4; ++ni) {
                    int c = (int)brow0 + wc + ni * 16 + fr;
                    float bv = bias[c];
                    int cv = c - 2048;
                    int r0 = (int)arow0 + wr + mi * 16 + fq;
                    int bb = r0 >> 11, t0 = r0 & 2047;
                    unsigned int lo = (unsigned int)f2bf(acc[mi][ni][0] + bv) |
                                      ((unsigned int)f2bf(acc[mi][ni][1] + bv) << 16);
                    unsigned int hi = (unsigned int)f2bf(acc[mi][ni][2] + bv) |
                                      ((unsigned int)f2bf(acc[mi][ni][3] + bv) << 16);
                    *(uint2*)&out1[(((size_t)(bb * 1024 + cv)) << 11) + t0] =
                        make_uint2(lo, hi);
                }
        } else {
            // q columns get 1/sqrt(D)=0.125 folded in (exact pow-2 scale)
            const float qs = ((int)(brow0 + wc) < 1024) ? 0.125f : 1.0f;
#pragma unroll
            for (int mi = 0; mi < 4; ++mi)
#pragma unroll
                for (int ni = 0; ni < 4; ++ni) {
                    size_t r = arow0 + wr + mi * 16 + fq;
                    size_t c = brow0 + wc + ni * 16 + fr;
                    float bv = bias[c];
#pragma unroll
                    for (int j = 0; j < 4; ++j)
                        ((unsigned short*)out0)[(r + j) * 2048 + c] =
                            f2bf((acc[mi][ni][j] + bv) * qs);
                }
        }
    }
}

// ---- MFMA flash attention ---------------------------------------------------
// Block: 128 q-rows (4 waves x 32), s-tiles of 64. K and V^T staged in LDS
// with XOR-16B swizzle. T14 async-stage: issue next tile's global loads before
// compute; vmcnt-drain + LDS write after the post-compute barrier.
__global__ __launch_bounds__(256, 2) void attn_mfma(
    const unsigned short* __restrict__ qk,  // [B*T][2048] bf16 (q*0.125 | k)
    const unsigned short* __restrict__ vt,  // [(b*1024+h*64+d)][T] bf16
    unsigned short* __restrict__ y,         // [B*T][1024] bf16
    int BH) {
    constexpr int T = 2048;

    __shared__ __align__(16) unsigned short sK[64 * 64];
    __shared__ __align__(16) unsigned short sV[64 * 64];  // V^T tile [d][s]
    __shared__ __align__(16) unsigned short sP[4][32 * 64];

    const int tid = threadIdx.x;
    const int lane = tid & 63;
    const int w = tid >> 6;
    const int l15 = lane & 15;
    const int g = lane >> 4;

    const int bh = blockIdx.x % BH;
    const int qt = 15 - blockIdx.x / BH;  // heavy q-tiles first
    const int b = bh >> 4;
    const int h = bh & 15;
    const int q0 = qt * 128;
    const int qw0 = q0 + w * 32;

    // Q fragments (A-frag: row=lane&15, k=(lane>>4)*8 within K=32 chunk)
    short8 aq[2][2];
    {
        const unsigned short* qbase = qk + ((size_t)(b * T + qw0)) * 2048 + h * 64;
#pragma unroll
        for (int mi = 0; mi < 2; ++mi)
#pragma unroll
            for (int kc = 0; kc < 2; ++kc)
                aq[mi][kc] = *(const short8*)(qbase + (size_t)(mi * 16 + l15) * 2048 +
                                              g * 8 + kc * 32);
    }

    f32x4 O[2][4] = {};
    float m_st[2][4], l_st[2][4];
#pragma unroll
    for (int mi = 0; mi < 2; ++mi)
#pragma unroll
        for (int r = 0; r < 4; ++r) { m_st[mi][r] = -1e30f; l_st[mi][r] = 0.f; }

    const unsigned short* kbase = qk + ((size_t)(b * T)) * 2048 + 1024 + h * 64;
    const unsigned short* vbase = vt + ((size_t)(b * 1024 + h * 64)) * 2048;
    unsigned short* sPw = sP[w];

    const int srow = tid >> 3;   // staging row 0..31 (+32)
    const int c16 = tid & 7;     // 16B column within 128B row
    const int swz = ((c16 ^ (srow & 7)) << 3);

    const int nt = (q0 + 128) >> 6;

    uint4 kd0, kd1, vd0, vd1;
    // prologue: stage tile 0
    kd0 = *(const uint4*)(kbase + (size_t)(srow) * 2048 + c16 * 8);
    kd1 = *(const uint4*)(kbase + (size_t)(srow + 32) * 2048 + c16 * 8);
    vd0 = *(const uint4*)(vbase + (size_t)srow * 2048 + c16 * 8);
    vd1 = *(const uint4*)(vbase + (size_t)(srow + 32) * 2048 + c16 * 8);
    *(uint4*)&sK[srow * 64 + swz] = kd0;
    *(uint4*)&sK[(srow + 32) * 64 + swz] = kd1;
    *(uint4*)&sV[srow * 64 + swz] = vd0;
    *(uint4*)&sV[(srow + 32) * 64 + swz] = vd1;
    __syncthreads();

    for (int it = 0; it < nt; ++it) {
        const int s0 = it << 6;
        const bool haveNext = (it + 1 < nt);
        if (haveNext) {
            const int s1 = s0 + 64;
            kd0 = *(const uint4*)(kbase + (size_t)(s1 + srow) * 2048 + c16 * 8);
            kd1 = *(const uint4*)(kbase + (size_t)(s1 + srow + 32) * 2048 + c16 * 8);
            vd0 = *(const uint4*)(vbase + (size_t)srow * 2048 + s1 + c16 * 8);
            vd1 = *(const uint4*)(vbase + (size_t)(srow + 32) * 2048 + s1 + c16 * 8);
        }

        if (s0 <= qw0 + 31) {  // not fully masked for this wave
            // ---- S = Q @ K^T ----
            f32x4 sacc[2][4] = {};
            {
                short8 bk[4][2];
#pragma unroll
                for (int ni = 0; ni < 4; ++ni) {
                    const int row = ni * 16 + l15;
#pragma unroll
                    for (int kc = 0; kc < 2; ++kc)
                        bk[ni][kc] = *(const short8*)&sK[row * 64 +
                                                         (((g + kc * 4) ^ (row & 7)) << 3)];
                }
#pragma unroll
                for (int kc = 0; kc < 2; ++kc)
#pragma unroll
                    for (int mi = 0; mi < 2; ++mi)
#pragma unroll
                        for (int ni = 0; ni < 4; ++ni)
                            sacc[mi][ni] = __builtin_amdgcn_mfma_f32_16x16x32_bf16(
                                aq[mi][kc], bk[ni][kc], sacc[mi][ni], 0, 0, 0);
            }

            // ---- online softmax (wave-parallel, 16-lane xor reduce) ----
            float f_sc[2][4];
#pragma unroll
            for (int mi = 0; mi < 2; ++mi) {
#pragma unroll
                for (int reg = 0; reg < 4; ++reg) {
                    const int q_loc = mi * 16 + g * 4 + reg;
                    const int qg = qw0 + q_loc;
                    float mx = -INFINITY;
#pragma unroll
                    for (int ni = 0; ni < 4; ++ni) {
                        float v = sacc[mi][ni][reg];
                        v = (s0 + ni * 16 + l15 <= qg) ? v : -INFINITY;
                        sacc[mi][ni][reg] = v;
                        mx = fmaxf(mx, v);
                    }
                    mx = fmaxf(mx, __shfl_xor(mx, 1));
                    mx = fmaxf(mx, __shfl_xor(mx, 2));
                    mx = fmaxf(mx, __shfl_xor(mx, 4));
                    mx = fmaxf(mx, __shfl_xor(mx, 8));
                    const float mn = fmaxf(m_st[mi][reg], mx);
                    const float f = __expf(m_st[mi][reg] - mn);
                    m_st[mi][reg] = mn;
                    f_sc[mi][reg] = f;
                    float rs = 0.f;
#pragma unroll
                    for (int ni = 0; ni < 4; ++ni) {
                        float p = __expf(sacc[mi][ni][reg] - mn);
                        rs += p;
                        const int s = ni * 16 + l15;
                        sPw[q_loc * 64 + ((((s >> 3) ^ (q_loc & 7)) << 3) | (s & 7))] =
                            f2bf(p);
                    }
                    rs += __shfl_xor(rs, 1);
                    rs += __shfl_xor(rs, 2);
                    rs += __shfl_xor(rs, 4);
                    rs += __shfl_xor(rs, 8);
                    l_st[mi][reg] = l_st[mi][reg] * f + rs;
                }
            }

            // ---- rescale O ----
#pragma unroll
            for (int mi = 0; mi < 2; ++mi)
#pragma unroll
                for (int di = 0; di < 4; ++di)
#pragma unroll
                    for (int reg = 0; reg < 4; ++reg)
                        O[mi][di][reg] *= f_sc[mi][reg];

            // ---- O += P @ V ----
            short8 aP[2][2], bv[4][2];
#pragma unroll
            for (int mi = 0; mi < 2; ++mi) {
                const int row = mi * 16 + l15;
#pragma unroll
                for (int kc = 0; kc < 2; ++kc)
                    aP[mi][kc] = *(const short8*)&sPw[row * 64 +
                                                      (((g + kc * 4) ^ (row & 7)) << 3)];
            }
#pragma unroll
            for (int di = 0; di < 4; ++di) {
                const int row = di * 16 + l15;
#pragma unroll
                for (int kc = 0; kc < 2; ++kc)
                    bv[di][kc] = *(const short8*)&sV[row * 64 +
                                                     (((g + kc * 4) ^ (row & 7)) << 3)];
            }
#pragma unroll
            for (int kc = 0; kc < 2; ++kc)
#pragma unroll
                for (int mi = 0; mi < 2; ++mi)
#pragma unroll
                    for (int di = 0; di < 4; ++di)
                        O[mi][di] = __builtin_amdgcn_mfma_f32_16x16x32_bf16(
                            aP[mi][kc], bv[di][kc], O[mi][di], 0, 0, 0);
        }

        __syncthreads();  // all reads of sK/sV done
        if (haveNext) {
            *(uint4*)&sK[srow * 64 + swz] = kd0;
            *(uint4*)&sK[(srow + 32) * 64 + swz] = kd1;
            *(uint4*)&sV[srow * 64 + swz] = vd0;
            *(uint4*)&sV[(srow + 32) * 64 + swz] = vd1;
            __syncthreads();  // writes visible before next compute
        }
    }

    // ---- normalize + write ----
#pragma unroll
    for (int mi = 0; mi < 2; ++mi) {
#pragma unroll
        for (int reg = 0; reg < 4; ++reg) {
            const float inv = 1.0f / l_st[mi][reg];
            const int q = qw0 + mi * 16 + g * 4 + reg;
            const size_t base = (size_t)(b * T + q) * 1024 + h * 64 + l15;
#pragma unroll
            for (int di = 0; di < 4; ++di)
                y[base + di * 16] = f2bf(O[mi][di][reg] * inv);
        }
    }
}

extern "C" void kernel_launch(void* const* d_in, const int* in_sizes, int n_in,
                              void* d_out, int out_size, void* d_ws, size_t ws_size,
                              hipStream_t stream) {
    const float* x      = (const float*)d_in[0];
    const float* w_attn = (const float*)d_in[1];
    const float* b_attn = (const float*)d_in[2];
    const float* w_proj = (const float*)d_in[3];
    const float* b_proj = (const float*)d_in[4];

    const int C = 1024, T = 2048, H = 16;
    const int B = in_sizes[0] / (T * C);
    const int M = B * T;

    // workspace (ushorts): xb | wTa | wTp | qk | vt   (75.5 MB total)
    unsigned short* xb  = (unsigned short*)d_ws;          // M*C
    unsigned short* wTa = xb + (size_t)M * C;             // 3C x C
    unsigned short* wTp = wTa + (size_t)3 * C * C;        // C x C
    unsigned short* qkb = wTp + (size_t)C * C;            // M x 2C
    unsigned short* vtb = qkb + (size_t)M * 2 * C;        // B*1024 x T
    unsigned short* y   = xb;                             // reuse after GEMM1

    int n4 = (M * C) / 4;
    conv_f32_to_bf16<<<(n4 + 255) / 256, 256, 0, stream>>>(x, xb, n4);
    transpose_f32_to_bf16<<<dim3(3 * C / 32, C / 32), dim3(32, 8), 0, stream>>>(
        w_attn, wTa, C, 3 * C);
    transpose_f32_to_bf16<<<dim3(C / 32, C / 32), dim3(32, 8), 0, stream>>>(
        w_proj, wTp, C, C);
    gemm_bt<2><<<dim3(M / 128, (3 * C) / 128), 256, 0, stream>>>(
        xb, wTa, b_attn, (void*)qkb, vtb, M, 3 * C, C);
    attn_mfma<<<dim3(B * H * (T / 128)), 256, 0, stream>>>(qkb, vtb, y, B * H);
    gemm_bt<0><<<dim3(M / 128, C / 128), 256, 0, stream>>>(
        y, wTp, b_proj, d_out, nullptr, M, C, C);
}

// Round 5
// 223.678 us; speedup vs baseline: 5.3615x; 1.0030x over previous
//
#include <hip/hip_runtime.h>
#include <hip/hip_bf16.h>

typedef short short8 __attribute__((ext_vector_type(8)));
typedef float f32x4 __attribute__((ext_vector_type(4)));

typedef __attribute__((address_space(1))) void as1_void;
typedef __attribute__((address_space(3))) void as3_void;

__device__ __forceinline__ unsigned short f2bf(float f) {
    __hip_bfloat16 h = __float2bfloat16(f);
    return __builtin_bit_cast(unsigned short, h);
}

// fast base-2 exp (v_exp_f32)
__device__ __forceinline__ float exp2fast(float x) {
    return __builtin_amdgcn_exp2f(x);
}

// async global->LDS, 16B per lane; lds dest = wave-uniform base + lane*16
__device__ __forceinline__ void gload16(const unsigned short* g, unsigned short* l) {
    __builtin_amdgcn_global_load_lds((as1_void*)g, (as3_void*)l, 16, 0, 0);
}

// ---- fp32 -> bf16 elementwise ----------------------------------------------
__global__ __launch_bounds__(256) void conv_f32_to_bf16(
    const float* __restrict__ in, unsigned short* __restrict__ out, int n4) {
    int i = blockIdx.x * 256 + threadIdx.x;
    if (i >= n4) return;
    float4 v = ((const float4*)in)[i];
    ushort4 o;
    o.x = f2bf(v.x); o.y = f2bf(v.y); o.z = f2bf(v.z); o.w = f2bf(v.w);
    ((ushort4*)out)[i] = o;
}

// ---- W[K][N] fp32 -> WT[N][K] bf16 -----------------------------------------
__global__ __launch_bounds__(256) void transpose_f32_to_bf16(
    const float* __restrict__ W, unsigned short* __restrict__ WT, int K, int N) {
    __shared__ float tile[32][33];
    int tx = threadIdx.x, ty = threadIdx.y;
    int n0 = blockIdx.x * 32, k0 = blockIdx.y * 32;
#pragma unroll
    for (int j = 0; j < 4; ++j)
        tile[ty + j * 8][tx] = W[(size_t)(k0 + ty + j * 8) * N + n0 + tx];
    __syncthreads();
#pragma unroll
    for (int j = 0; j < 4; ++j)
        WT[(size_t)(n0 + ty + j * 8) * K + k0 + tx] = f2bf(tile[tx][ty + j * 8]);
}

// ---- GEMM: C[M,N] = A[M,K]bf16 @ Bt[N,K]^T + bias --------------------------
// global_load_lds staging (m97 structure). MODE 0: fp32 out, stride N.
// MODE 2: qkv split: cols<1024 -> bf16 q*(0.125*log2e); 1024..2047 -> bf16 k;
//         cols>=2048 -> bf16 vt[(b*1024 + c-2048)][t] (transposed V).
template <int MODE>
__global__ __launch_bounds__(256, 2) void gemm_bt(
    const unsigned short* __restrict__ A,
    const unsigned short* __restrict__ Bt,
    const float* __restrict__ bias,
    void* __restrict__ out0,
    unsigned short* __restrict__ out1,
    int M, int N, int K) {
    __shared__ unsigned short sA[128 * 32];
    __shared__ unsigned short sB[128 * 32];
    const int tid = threadIdx.x;
    const int lane = tid & 63;
    const int w = tid >> 6;
    const int wr = (w >> 1) * 64;
    const int wc = (w & 1) * 64;
    const size_t arow0 = (size_t)blockIdx.x * 128;
    const size_t brow0 = (size_t)blockIdx.y * 128;

    const int grow = (w << 5) + (lane >> 2);
    const int gcol = (lane & 3) << 3;
    const unsigned short* pA0 = A + (arow0 + grow) * (size_t)K + gcol;
    const unsigned short* pB0 = Bt + (brow0 + grow) * (size_t)K + gcol;
    unsigned short* lA = sA + (w << 10);
    unsigned short* lB = sB + (w << 10);

    f32x4 acc[4][4] = {};
    const int fr = lane & 15;
    const int fk = (lane >> 4) << 3;

    for (int k0 = 0; k0 < K; k0 += 32) {
        __syncthreads();
        gload16(pA0 + k0, lA);
        gload16(pA0 + 16 * (size_t)K + k0, lA + 512);
        gload16(pB0 + k0, lB);
        gload16(pB0 + 16 * (size_t)K + k0, lB + 512);
        __syncthreads();

        short8 af[4], bfr[4];
#pragma unroll
        for (int i = 0; i < 4; ++i)
            af[i] = *(const short8*)&sA[(wr + i * 16 + fr) * 32 + fk];
#pragma unroll
        for (int i = 0; i < 4; ++i)
            bfr[i] = *(const short8*)&sB[(wc + i * 16 + fr) * 32 + fk];
#pragma unroll
        for (int mi = 0; mi < 4; ++mi)
#pragma unroll
            for (int ni = 0; ni < 4; ++ni)
                acc[mi][ni] = __builtin_amdgcn_mfma_f32_16x16x32_bf16(
                    af[mi], bfr[ni], acc[mi][ni], 0, 0, 0);
    }

    const int fq = (lane >> 4) << 2;
    if constexpr (MODE == 0) {
#pragma unroll
        for (int mi = 0; mi < 4; ++mi)
#pragma unroll
            for (int ni = 0; ni < 4; ++ni) {
                size_t r = arow0 + wr + mi * 16 + fq;
                size_t c = brow0 + wc + ni * 16 + fr;
                float bv = bias[c];
#pragma unroll
                for (int j = 0; j < 4; ++j)
                    ((float*)out0)[(r + j) * (size_t)N + c] = acc[mi][ni][j] + bv;
            }
    } else {
        const bool isv = (int)(brow0 + wc) >= 2048;
        if (isv) {
#pragma unroll
            for (int mi = 0; mi < 4; ++mi)
#pragma unroll
                for (int ni = 0; ni < 4; ++ni) {
                    int c = (int)brow0 + wc + ni * 16 + fr;
                    float bv = bias[c];
                    int cv = c - 2048;
                    int r0 = (int)arow0 + wr + mi * 16 + fq;
                    int bb = r0 >> 11, t0 = r0 & 2047;
                    unsigned int lo = (unsigned int)f2bf(acc[mi][ni][0] + bv) |
                                      ((unsigned int)f2bf(acc[mi][ni][1] + bv) << 16);
                    unsigned int hi = (unsigned int)f2bf(acc[mi][ni][2] + bv) |
                                      ((unsigned int)f2bf(acc[mi][ni][3] + bv) << 16);
                    *(uint2*)&out1[(((size_t)(bb * 1024 + cv)) << 11) + t0] =
                        make_uint2(lo, hi);
                }
        } else {
            // q columns: fold 1/sqrt(D) * log2(e) so attention runs in exp2 domain
            const float qs = ((int)(brow0 + wc) < 1024) ? 0.125f * 1.4426950408889634f
                                                        : 1.0f;
#pragma unroll
            for (int mi = 0; mi < 4; ++mi)
#pragma unroll
                for (int ni = 0; ni < 4; ++ni) {
                    size_t r = arow0 + wr + mi * 16 + fq;
                    size_t c = brow0 + wc + ni * 16 + fr;
                    float bv = bias[c];
#pragma unroll
                    for (int j = 0; j < 4; ++j)
                        ((unsigned short*)out0)[(r + j) * 2048 + c] =
                            f2bf((acc[mi][ni][j] + bv) * qs);
                }
        }
    }
}

// ---- MFMA flash attention ---------------------------------------------------
// Block: pair of q-tiles (qt=15-p then qt=p) -> uniform 34 s-tiles per block.
// 4 waves x 32 q-rows, s-tiles of 64. K,V^T staged in swizzled LDS.
// exp2-domain softmax; l computed via MFMA against all-ones B fragment.
__global__ __launch_bounds__(256, 2) void attn_mfma(
    const unsigned short* __restrict__ qk,  // [B*T][2048] bf16 (q*scale | k)
    const unsigned short* __restrict__ vt,  // [(b*1024+h*64+d)][T] bf16
    unsigned short* __restrict__ y,         // [B*T][1024] bf16
    int BH) {
    constexpr int T = 2048;

    __shared__ __align__(16) unsigned short sK[64 * 64];
    __shared__ __align__(16) unsigned short sV[64 * 64];  // V^T tile [d][s]
    __shared__ __align__(16) unsigned short sP[4][32 * 64];

    const int tid = threadIdx.x;
    const int lane = tid & 63;
    const int w = tid >> 6;
    const int l15 = lane & 15;
    const int g = lane >> 4;

    const int bh = blockIdx.x % BH;
    const int p = blockIdx.x / BH;  // 0..7 pair index
    const int b = bh >> 4;
    const int h = bh & 15;

    const unsigned short* kbase = qk + ((size_t)(b * T)) * 2048 + 1024 + h * 64;
    const unsigned short* vbase = vt + ((size_t)(b * 1024 + h * 64)) * 2048;
    unsigned short* sPw = sP[w];

    const int srow = tid >> 3;   // staging row 0..31 (+32)
    const int c16 = tid & 7;     // 16B column within 128B row
    const int swz = ((c16 ^ (srow & 7)) << 3);

    short8 vones;
#pragma unroll
    for (int i = 0; i < 8; ++i) vones[i] = (short)0x3F80;  // bf16 1.0

    for (int half = 0; half < 2; ++half) {
        const int qt = half ? p : (15 - p);  // heavy q-tile first
        const int q0 = qt << 7;
        const int qw0 = q0 + w * 32;

        // Q fragments (A-frag: row=lane&15, k=(lane>>4)*8 within K=32 chunk)
        short8 aq[2][2];
        {
            const unsigned short* qbase =
                qk + ((size_t)(b * T + qw0)) * 2048 + h * 64;
#pragma unroll
            for (int mi = 0; mi < 2; ++mi)
#pragma unroll
                for (int kc = 0; kc < 2; ++kc)
                    aq[mi][kc] = *(const short8*)(qbase +
                                                  (size_t)(mi * 16 + l15) * 2048 +
                                                  g * 8 + kc * 32);
        }

        f32x4 O[2][4] = {};
        float m_st[2][4], l_st[2][4];
#pragma unroll
        for (int mi = 0; mi < 2; ++mi)
#pragma unroll
            for (int r = 0; r < 4; ++r) { m_st[mi][r] = -1e30f; l_st[mi][r] = 0.f; }

        const int nt = (q0 + 128) >> 6;

        uint4 kd0, kd1, vd0, vd1;
        __syncthreads();  // prior half's readers done before overwriting tiles
        kd0 = *(const uint4*)(kbase + (size_t)(srow) * 2048 + c16 * 8);
        kd1 = *(const uint4*)(kbase + (size_t)(srow + 32) * 2048 + c16 * 8);
        vd0 = *(const uint4*)(vbase + (size_t)srow * 2048 + c16 * 8);
        vd1 = *(const uint4*)(vbase + (size_t)(srow + 32) * 2048 + c16 * 8);
        *(uint4*)&sK[srow * 64 + swz] = kd0;
        *(uint4*)&sK[(srow + 32) * 64 + swz] = kd1;
        *(uint4*)&sV[srow * 64 + swz] = vd0;
        *(uint4*)&sV[(srow + 32) * 64 + swz] = vd1;
        __syncthreads();

        for (int it = 0; it < nt; ++it) {
            const int s0 = it << 6;
            const bool haveNext = (it + 1 < nt);
            if (haveNext) {
                const int s1 = s0 + 64;
                kd0 = *(const uint4*)(kbase + (size_t)(s1 + srow) * 2048 + c16 * 8);
                kd1 = *(const uint4*)(kbase + (size_t)(s1 + srow + 32) * 2048 + c16 * 8);
                vd0 = *(const uint4*)(vbase + (size_t)srow * 2048 + s1 + c16 * 8);
                vd1 = *(const uint4*)(vbase + (size_t)(srow + 32) * 2048 + s1 + c16 * 8);
            }

            if (s0 <= qw0 + 31) {  // not fully masked for this wave
                // ---- S = Q @ K^T (exp2-domain scores) ----
                f32x4 sacc[2][4] = {};
                {
                    short8 bk[4][2];
#pragma unroll
                    for (int ni = 0; ni < 4; ++ni) {
                        const int row = ni * 16 + l15;
#pragma unroll
                        for (int kc = 0; kc < 2; ++kc)
                            bk[ni][kc] = *(const short8*)&sK[row * 64 +
                                                             (((g + kc * 4) ^ (row & 7))
                                                              << 3)];
                    }
                    __builtin_amdgcn_s_setprio(1);
#pragma unroll
                    for (int kc = 0; kc < 2; ++kc)
#pragma unroll
                        for (int mi = 0; mi < 2; ++mi)
#pragma unroll
                            for (int ni = 0; ni < 4; ++ni)
                                sacc[mi][ni] = __builtin_amdgcn_mfma_f32_16x16x32_bf16(
                                    aq[mi][kc], bk[ni][kc], sacc[mi][ni], 0, 0, 0);
                    __builtin_amdgcn_s_setprio(0);
                }

                // ---- online softmax: max reduce only (sum via MFMA below) ----
                const bool needMask = (s0 + 63 > qw0);  // wave-uniform
                float f_sc[2][4];
#pragma unroll
                for (int mi = 0; mi < 2; ++mi) {
#pragma unroll
                    for (int reg = 0; reg < 4; ++reg) {
                        const int q_loc = mi * 16 + g * 4 + reg;
                        if (needMask) {
                            const int qg = qw0 + q_loc;
#pragma unroll
                            for (int ni = 0; ni < 4; ++ni) {
                                float v = sacc[mi][ni][reg];
                                sacc[mi][ni][reg] =
                                    (s0 + ni * 16 + l15 <= qg) ? v : -INFINITY;
                            }
                        }
                        float mx = fmaxf(fmaxf(sacc[mi][0][reg], sacc[mi][1][reg]),
                                         fmaxf(sacc[mi][2][reg], sacc[mi][3][reg]));
                        mx = fmaxf(mx, __shfl_xor(mx, 1));
                        mx = fmaxf(mx, __shfl_xor(mx, 2));
                        mx = fmaxf(mx, __shfl_xor(mx, 4));
                        mx = fmaxf(mx, __shfl_xor(mx, 8));
                        const float mn = fmaxf(m_st[mi][reg], mx);
                        const float f = exp2fast(m_st[mi][reg] - mn);
                        m_st[mi][reg] = mn;
                        f_sc[mi][reg] = f;
#pragma unroll
                        for (int ni = 0; ni < 4; ++ni) {
                            float pv = exp2fast(sacc[mi][ni][reg] - mn);
                            const int s = ni * 16 + l15;
                            sPw[q_loc * 64 +
                                ((((s >> 3) ^ (q_loc & 7)) << 3) | (s & 7))] = f2bf(pv);
                        }
                    }
                }

                // ---- rescale O ----
#pragma unroll
                for (int mi = 0; mi < 2; ++mi)
#pragma unroll
                    for (int di = 0; di < 4; ++di)
#pragma unroll
                        for (int reg = 0; reg < 4; ++reg)
                            O[mi][di][reg] *= f_sc[mi][reg];

                // ---- l (row-sum of P) via MFMA-ones, then O += P @ V ----
                short8 aP[2][2], bv[4][2];
#pragma unroll
                for (int mi = 0; mi < 2; ++mi) {
                    const int row = mi * 16 + l15;
#pragma unroll
                    for (int kc = 0; kc < 2; ++kc)
                        aP[mi][kc] = *(const short8*)&sPw[row * 64 +
                                                          (((g + kc * 4) ^ (row & 7))
                                                           << 3)];
                }
#pragma unroll
                for (int di = 0; di < 4; ++di) {
                    const int row = di * 16 + l15;
#pragma unroll
                    for (int kc = 0; kc < 2; ++kc)
                        bv[di][kc] = *(const short8*)&sV[row * 64 +
                                                         (((g + kc * 4) ^ (row & 7))
                                                          << 3)];
                }
                f32x4 lacc[2] = {};
                __builtin_amdgcn_s_setprio(1);
#pragma unroll
                for (int kc = 0; kc < 2; ++kc)
#pragma unroll
                    for (int mi = 0; mi < 2; ++mi)
                        lacc[mi] = __builtin_amdgcn_mfma_f32_16x16x32_bf16(
                            aP[mi][kc], vones, lacc[mi], 0, 0, 0);
#pragma unroll
                for (int kc = 0; kc < 2; ++kc)
#pragma unroll
                    for (int mi = 0; mi < 2; ++mi)
#pragma unroll
                        for (int di = 0; di < 4; ++di)
                            O[mi][di] = __builtin_amdgcn_mfma_f32_16x16x32_bf16(
                                aP[mi][kc], bv[di][kc], O[mi][di], 0, 0, 0);
                __builtin_amdgcn_s_setprio(0);
#pragma unroll
                for (int mi = 0; mi < 2; ++mi)
#pragma unroll
                    for (int reg = 0; reg < 4; ++reg)
                        l_st[mi][reg] = l_st[mi][reg] * f_sc[mi][reg] + lacc[mi][reg];
            }

            __syncthreads();  // all reads of sK/sV done
            if (haveNext) {
                *(uint4*)&sK[srow * 64 + swz] = kd0;
                *(uint4*)&sK[(srow + 32) * 64 + swz] = kd1;
                *(uint4*)&sV[srow * 64 + swz] = vd0;
                *(uint4*)&sV[(srow + 32) * 64 + swz] = vd1;
                __syncthreads();
            }
        }

        // ---- normalize + write ----
#pragma unroll
        for (int mi = 0; mi < 2; ++mi) {
#pragma unroll
            for (int reg = 0; reg < 4; ++reg) {
                const float inv = 1.0f / l_st[mi][reg];
                const int q = qw0 + mi * 16 + g * 4 + reg;
                const size_t base = (size_t)(b * T + q) * 1024 + h * 64 + l15;
#pragma unroll
                for (int di = 0; di < 4; ++di)
                    y[base + di * 16] = f2bf(O[mi][di][reg] * inv);
            }
        }
    }
}

extern "C" void kernel_launch(void* const* d_in, const int* in_sizes, int n_in,
                              void* d_out, int out_size, void* d_ws, size_t ws_size,
                              hipStream_t stream) {
    const float* x      = (const float*)d_in[0];
    const float* w_attn = (const float*)d_in[1];
    const float* b_attn = (const float*)d_in[2];
    const float* w_proj = (const float*)d_in[3];
    const float* b_proj = (const float*)d_in[4];

    const int C = 1024, T = 2048, H = 16;
    const int B = in_sizes[0] / (T * C);
    const int M = B * T;

    // workspace (ushorts): xb | wTa | wTp | qk | vt   (75.5 MB total)
    unsigned short* xb  = (unsigned short*)d_ws;          // M*C
    unsigned short* wTa = xb + (size_t)M * C;             // 3C x C
    unsigned short* wTp = wTa + (size_t)3 * C * C;        // C x C
    unsigned short* qkb = wTp + (size_t)C * C;            // M x 2C
    unsigned short* vtb = qkb + (size_t)M * 2 * C;        // B*1024 x T
    unsigned short* y   = xb;                             // reuse after GEMM1

    int n4 = (M * C) / 4;
    conv_f32_to_bf16<<<(n4 + 255) / 256, 256, 0, stream>>>(x, xb, n4);
    transpose_f32_to_bf16<<<dim3(3 * C / 32, C / 32), dim3(32, 8), 0, stream>>>(
        w_attn, wTa, C, 3 * C);
    transpose_f32_to_bf16<<<dim3(C / 32, C / 32), dim3(32, 8), 0, stream>>>(
        w_proj, wTp, C, C);
    gemm_bt<2><<<dim3(M / 128, (3 * C) / 128), 256, 0, stream>>>(
        xb, wTa, b_attn, (void*)qkb, vtb, M, 3 * C, C);
    attn_mfma<<<dim3((B * H) * 8), 256, 0, stream>>>(qkb, vtb, y, B * H);
    gemm_bt<0><<<dim3(M / 128, C / 128), 256, 0, stream>>>(
        y, wTp, b_proj, d_out, nullptr, M, C, C);
}